// Round 3
// baseline (1047.187 us; speedup 1.0000x reference)
//
#include <hip/hip_runtime.h>
#include <cmath>

// DTASNN embedding: T=5 recurrent steps, each = conv(x, w_in) + conv(spike_prev, w_gate)
// (both 64ch -> 128ch, 3x3 SAME), sigmoid-gated LIF update, hard reset, avg readout.
//
// R3 changes vs R2 (which was LDS-bound: 2-way b128 quad conflicts + 2 barriers/ci):
//  - lane remap: octets (8 consecutive lanes) span 8 ROWS at fixed strip, so each
//    octet's b128 reads hit 8 distinct bank-quads (17*h mod 8 covers all residues)
//    -> conflict-free under the octet service model of ds_read_b128.
//  - double-buffered LDS planes -> 1 barrier per ci instead of 2.
//
// ws layout (floats): vmem [2M] | spikeA [2M] | spikeB [2M]

#define HW    64
#define CIN   64
#define COUT  64
#define TT    5
#define PLANE (HW * HW)            // 4096
#define LSTRIDE 68                 // odd multiple of 4 dwords: 17 quads/row
#define LROWS   66                 // top halo + 64 interior + bottom halo
#define LPLANE  (LROWS * LSTRIDE + 4)  // +4: last b128 read overhangs row 65

// Accumulate 4 convolutions (same input plane, 4 weight sets) into 4 8-wide strips.
__device__ __forceinline__ void conv_accum4(const float* __restrict__ lds,
    int h, int w0,
    const float* __restrict__ wa, const float* __restrict__ wb,
    const float* __restrict__ wc, const float* __restrict__ wd,
    float* __restrict__ A, float* __restrict__ B,
    float* __restrict__ C, float* __restrict__ D)
{
#pragma unroll
  for (int kh = 0; kh < 3; ++kh) {
    float r[16];
    const float4* rp = (const float4*)(lds + (h + kh) * LSTRIDE + w0);
#pragma unroll
    for (int q = 0; q < 4; ++q) {
      float4 v = rp[q];
      r[4*q+0] = v.x; r[4*q+1] = v.y; r[4*q+2] = v.z; r[4*q+3] = v.w;
    }
#pragma unroll
    for (int kw = 0; kw < 3; ++kw) {
      const float fa = wa[kh*3+kw], fb = wb[kh*3+kw];
      const float fc = wc[kh*3+kw], fd = wd[kh*3+kw];
#pragma unroll
      for (int j = 0; j < 8; ++j) {
        const float x = r[3 + j + kw];   // col w0+j-1+kw (dword col+4, halo at 3/68)
        A[j] = fmaf(x, fa, A[j]);
        B[j] = fmaf(x, fb, B[j]);
        C[j] = fmaf(x, fc, C[j]);
        D[j] = fmaf(x, fd, D[j]);
      }
    }
  }
}

__global__ __launch_bounds__(512) void snn_step(
    const float* __restrict__ events,
    const float* __restrict__ w_in,
    const float* __restrict__ b_in,
    const float* __restrict__ w_gate,
    const float* __restrict__ b_gate,
    const float* __restrict__ tdecay,
    float* __restrict__ vmem,
    const float* __restrict__ s_src,
    float* __restrict__ s_dst,
    float* __restrict__ outp,
    int t)
{
  __shared__ float lx[2 * LPLANE];   // event plane, double-buffered (zero halo = SAME pad)
  __shared__ float ls[2 * LPLANE];   // spike plane, double-buffered

  const int tid = threadIdx.x;
  const int blk = blockIdx.x;              // 256 blocks = b(8) x co-pair(32)
  const int b   = blk >> 5;
  const int co0 = (blk & 31) * 2;
  const int co1 = co0 + 1;

  // Octet-friendly mapping: 8 consecutive lanes = 8 consecutive rows, same strip.
  const int h  = ((tid >> 6) << 3) | (tid & 7);  // row 0..63
  const int m  = (tid >> 3) & 7;                 // strip 0..7
  const int w0 = m * 8;

  // Zero both buffers once; interiors overwritten each ci, halos stay 0 (SAME pad).
  for (int i = tid; i < 2 * LPLANE; i += 512) { lx[i] = 0.f; ls[i] = 0.f; }

  float ac0[8], ag0[8], ac1[8], ag1[8];
#pragma unroll
  for (int j = 0; j < 8; ++j) { ac0[j]=0.f; ag0[j]=0.f; ac1[j]=0.f; ag1[j]=0.f; }

  // time-reversed events: step t reads events[b, TT-1-t]
  const float* evb = events + (size_t)(b * TT + (TT - 1 - t)) * CIN * PLANE + h * HW + w0;
  const float* ssb = s_src  + (size_t)b * CIN * PLANE + h * HW + w0;
  const int dbase = (h + 1) * LSTRIDE + (w0 + 4);  // interior cols at dword 4..67

  // prefetch ci=0
  float4 x0 = ((const float4*)evb)[0], x1 = ((const float4*)evb)[1];
  float4 s0 = ((const float4*)ssb)[0], s1 = ((const float4*)ssb)[1];

  __syncthreads();                         // zeroing complete before first stores

  for (int ci = 0; ci < CIN; ++ci) {
    const int pb = (ci & 1) * LPLANE;
    float* dlx = lx + pb + dbase;
    float* dls = ls + pb + dbase;
    ((float4*)dlx)[0] = x0; ((float4*)dlx)[1] = x1;
    ((float4*)dls)[0] = s0; ((float4*)dls)[1] = s1;

    if (ci + 1 < CIN) {                    // issue next-ci loads ahead of compute
      const float* nx = evb + (ci + 1) * PLANE;
      const float* ns = ssb + (ci + 1) * PLANE;
      x0 = ((const float4*)nx)[0]; x1 = ((const float4*)nx)[1];
      s0 = ((const float4*)ns)[0]; s1 = ((const float4*)ns)[1];
    }

    __syncthreads();                       // stores to pb visible; other buffer free

    // weights are block-uniform -> scalar loads, SGPR-operand FMAs
    const float* wi_a = w_in   + (size_t)(co0 * CIN + ci) * 9;          // cur, co0
    const float* wi_b = w_in   + (size_t)((co0 + COUT) * CIN + ci) * 9; // gate, co0
    const float* wi_c = w_in   + (size_t)(co1 * CIN + ci) * 9;
    const float* wi_d = w_in   + (size_t)((co1 + COUT) * CIN + ci) * 9;
    conv_accum4(lx + pb, h, w0, wi_a, wi_b, wi_c, wi_d, ac0, ag0, ac1, ag1);

    const float* wg_a = w_gate + (size_t)(co0 * CIN + ci) * 9;
    const float* wg_b = w_gate + (size_t)((co0 + COUT) * CIN + ci) * 9;
    const float* wg_c = w_gate + (size_t)(co1 * CIN + ci) * 9;
    const float* wg_d = w_gate + (size_t)((co1 + COUT) * CIN + ci) * 9;
    conv_accum4(ls + pb, h, w0, wg_a, wg_b, wg_c, wg_d, ac0, ag0, ac1, ag1);
  }

  const float tf = (float)t;
  const bool t0 = (t == 0);
  const bool tL = (t == TT - 1);

  auto epilog = [&](const float* ac, const float* ag, int co) {
    const float bc = b_in[co]        + b_gate[co];
    const float bg = b_in[co + COUT] + b_gate[co + COUT];
    const float th = powf(tdecay[co], tf);        // THRESH=1.0
    const size_t base = (size_t)((b * COUT + co) * HW + h) * HW + w0;
    float* vp = vmem  + base;
    float* sp = s_dst + base;
    float* op = outp  + base;
#pragma unroll
    for (int j = 0; j < 8; ++j) {
      const float cur  = ac[j] + bc;
      const float gp   = ag[j] + bg;
      const float gate = 1.f / (1.f + expf(-gp));
      const float v    = gate * vp[j] + cur;      // vmem = gate*vmem + current
      const bool fired = (v >= th);               // heaviside(v - th)
      vp[j] = fired ? 0.f : v;                    // hard reset to VRESET=0
      sp[j] = fired ? 1.f : 0.f;
      float o = (t0 ? 0.f : op[j]) + (fired ? 1.f : 0.f);
      if (tL) o *= 0.2f;                          // mean over T=5
      op[j] = o;
    }
  };
  epilog(ac0, ag0, co0);
  epilog(ac1, ag1, co1);
}

extern "C" void kernel_launch(void* const* d_in, const int* in_sizes, int n_in,
                              void* d_out, int out_size, void* d_ws, size_t ws_size,
                              hipStream_t stream) {
  const float* events = (const float*)d_in[0];
  const float* w_in   = (const float*)d_in[1];
  const float* b_in   = (const float*)d_in[2];
  const float* w_gate = (const float*)d_in[3];
  const float* b_gate = (const float*)d_in[4];
  const float* tdec   = (const float*)d_in[5];
  float* out = (float*)d_out;

  float* ws   = (float*)d_ws;
  const size_t NP = (size_t)8 * COUT * PLANE;   // 2,097,152
  float* vmem = ws;
  float* sA   = ws + NP;
  float* sB   = ws + 2 * NP;

  // zero vmem + spikeA (spikeB fully written at t=0 before first read)
  hipMemsetAsync(d_ws, 0, 2 * NP * sizeof(float), stream);

  dim3 grid(256), block(512);
  for (int t = 0; t < TT; ++t) {
    const float* ssrc = (t & 1) ? sB : sA;
    float*       sdst = (t & 1) ? sA : sB;
    hipLaunchKernelGGL(snn_step, grid, block, 0, stream,
                       events, w_in, b_in, w_gate, b_gate, tdec,
                       vmem, ssrc, sdst, out, t);
  }
}

// Round 4
// 1030.073 us; speedup vs baseline: 1.0166x; 1.0166x over previous
//
#include <hip/hip_runtime.h>
#include <cmath>

// DTASNN embedding: T=5 recurrent steps, each = conv(x, w_in) + conv(spike_prev, w_gate)
// (both 64ch -> 128ch, 3x3 SAME), sigmoid-gated LIF update, hard reset, avg readout.
//
// R4 changes vs R3 (which was latency-bound at 1.8 waves/SIMD, pipes <70% busy):
//  - 4-px strips, 1024 threads/block -> 16 waves/CU (2x latency hiding), same
//    total VALU work and same per-CU LDS dword traffic.
//  - exact-fit LDS reads per row: ds_read_b128 (4 center dwords) + ds_read2_b32
//    (2 edge dwords) = 6 dwords fetched / 6 needed (was 16/10).
//  - prefetch issued AFTER the barrier so the compiler's vmcnt(0)-before-s_barrier
//    drain happens a full compute-phase after issue.
//  - right halo trick: img col c of row r lives at dword r*68 + c + 4; col 64
//    (halo) = dword (r+1)*68 + 0, which is never written and stays zero.
//
// Per-output accumulation chains are bit-identical to R2/R3 (ci -> w_in taps
// kh,kw -> w_gate taps kh,kw) -> output is bit-exact vs the passing kernel.
//
// ws layout (floats): vmem [2M] | spikeA [2M] | spikeB [2M]

#define HW    64
#define CIN   64
#define COUT  64
#define TT    5
#define PLANE (HW * HW)            // 4096
#define LSTRIDE 68                 // dwords per LDS row
#define LROWS   66                 // top halo + 64 interior + bottom halo
#define LPLANE  (LROWS * LSTRIDE + 4)

// Accumulate 4 convolutions (same input plane, 4 weight sets) into 4 4-px strips.
__device__ __forceinline__ void conv_accum4(const float* __restrict__ lds,
    int h, int w0,
    const float* __restrict__ wa, const float* __restrict__ wb,
    const float* __restrict__ wc, const float* __restrict__ wd,
    float* __restrict__ A, float* __restrict__ B,
    float* __restrict__ C, float* __restrict__ D)
{
#pragma unroll
  for (int kh = 0; kh < 3; ++kh) {
    const float* row = lds + (h + kh) * LSTRIDE + w0;   // dword w0 = img col w0-4
    float v[6];                                         // img cols w0-1 .. w0+4
    float4 q = *(const float4*)(row + 4);               // img cols w0..w0+3 (aligned)
    v[0] = row[3];                                      // img col w0-1   } merged to
    v[5] = row[8];                                      // img col w0+4   } ds_read2_b32
    v[1] = q.x; v[2] = q.y; v[3] = q.z; v[4] = q.w;
#pragma unroll
    for (int kw = 0; kw < 3; ++kw) {
      const float fa = wa[kh*3+kw], fb = wb[kh*3+kw];
      const float fc = wc[kh*3+kw], fd = wd[kh*3+kw];
#pragma unroll
      for (int j = 0; j < 4; ++j) {
        const float x = v[j + kw];                      // img col w0+j-1+kw
        A[j] = fmaf(x, fa, A[j]);
        B[j] = fmaf(x, fb, B[j]);
        C[j] = fmaf(x, fc, C[j]);
        D[j] = fmaf(x, fd, D[j]);
      }
    }
  }
}

__global__ __launch_bounds__(1024, 4) void snn_step(
    const float* __restrict__ events,
    const float* __restrict__ w_in,
    const float* __restrict__ b_in,
    const float* __restrict__ w_gate,
    const float* __restrict__ b_gate,
    const float* __restrict__ tdecay,
    float* __restrict__ vmem,
    const float* __restrict__ s_src,
    float* __restrict__ s_dst,
    float* __restrict__ outp,
    int t)
{
  __shared__ float lx[2 * LPLANE];   // event plane, double-buffered
  __shared__ float ls[2 * LPLANE];   // spike plane, double-buffered

  const int tid = threadIdx.x;             // 0..1023
  const int blk = blockIdx.x;              // 256 blocks = b(8) x co-pair(32)
  const int b   = blk >> 5;
  const int co0 = (blk & 31) * 2;
  const int co1 = co0 + 1;

  const int h  = tid >> 4;                 // 64 rows, 16 threads/row
  const int w0 = (tid & 15) * 4;           // 4-wide strip per thread

  // Zero both buffers once. Interior (dwords 4..67 of rows 1..64) is rewritten
  // each ci; dwords 0..3 of every row and rows 0/65 stay 0 (SAME padding; dword
  // r*68+0 doubles as right halo col 64 of row r-1).
  for (int i = tid; i < 2 * LPLANE; i += 1024) { lx[i] = 0.f; ls[i] = 0.f; }

  float ac0[4], ag0[4], ac1[4], ag1[4];
#pragma unroll
  for (int j = 0; j < 4; ++j) { ac0[j]=0.f; ag0[j]=0.f; ac1[j]=0.f; ag1[j]=0.f; }

  // time-reversed events: step t reads events[b, TT-1-t]
  const float* evb = events + (size_t)(b * TT + (TT - 1 - t)) * CIN * PLANE + h * HW + w0;
  const float* ssb = s_src  + (size_t)b * CIN * PLANE + h * HW + w0;
  const int dbase = (h + 1) * LSTRIDE + (w0 + 4);   // 16B-aligned interior slot

  // prefetch ci=0 (one float4 per plane; wave covers 4 contiguous rows = 1 KiB)
  float4 x0 = *(const float4*)evb;
  float4 s0 = *(const float4*)ssb;

  __syncthreads();                         // zeroing complete before first stores

  for (int ci = 0; ci < CIN; ++ci) {
    const int pb = (ci & 1) * LPLANE;
    *(float4*)(lx + pb + dbase) = x0;
    *(float4*)(ls + pb + dbase) = s0;

    __syncthreads();                       // stores visible; prev buffer's readers done

    if (ci + 1 < CIN) {                    // issue next-ci loads AFTER barrier:
      const float* nx = evb + (ci + 1) * PLANE;   // vmcnt(0) drain at NEXT barrier,
      const float* ns = ssb + (ci + 1) * PLANE;   // a full compute-phase later
      x0 = *(const float4*)nx;
      s0 = *(const float4*)ns;
    }

    // weights are block-uniform -> scalar loads, SGPR-operand FMAs
    const float* wi_a = w_in   + (size_t)(co0 * CIN + ci) * 9;          // cur, co0
    const float* wi_b = w_in   + (size_t)((co0 + COUT) * CIN + ci) * 9; // gate, co0
    const float* wi_c = w_in   + (size_t)(co1 * CIN + ci) * 9;
    const float* wi_d = w_in   + (size_t)((co1 + COUT) * CIN + ci) * 9;
    conv_accum4(lx + pb, h, w0, wi_a, wi_b, wi_c, wi_d, ac0, ag0, ac1, ag1);

    const float* wg_a = w_gate + (size_t)(co0 * CIN + ci) * 9;
    const float* wg_b = w_gate + (size_t)((co0 + COUT) * CIN + ci) * 9;
    const float* wg_c = w_gate + (size_t)(co1 * CIN + ci) * 9;
    const float* wg_d = w_gate + (size_t)((co1 + COUT) * CIN + ci) * 9;
    conv_accum4(ls + pb, h, w0, wg_a, wg_b, wg_c, wg_d, ac0, ag0, ac1, ag1);
  }

  const float tf = (float)t;
  const bool t0 = (t == 0);
  const bool tL = (t == TT - 1);

  auto epilog = [&](const float* ac, const float* ag, int co) {
    const float bc = b_in[co]        + b_gate[co];
    const float bg = b_in[co + COUT] + b_gate[co + COUT];
    const float th = powf(tdecay[co], tf);        // THRESH=1.0
    const size_t base = (size_t)((b * COUT + co) * HW + h) * HW + w0;
    float* vp = vmem  + base;
    float* sp = s_dst + base;
    float* op = outp  + base;
#pragma unroll
    for (int j = 0; j < 4; ++j) {
      const float cur  = ac[j] + bc;
      const float gp   = ag[j] + bg;
      const float gate = 1.f / (1.f + expf(-gp));
      const float v    = gate * vp[j] + cur;      // vmem = gate*vmem + current
      const bool fired = (v >= th);               // heaviside(v - th)
      vp[j] = fired ? 0.f : v;                    // hard reset to VRESET=0
      sp[j] = fired ? 1.f : 0.f;
      float o = (t0 ? 0.f : op[j]) + (fired ? 1.f : 0.f);
      if (tL) o *= 0.2f;                          // mean over T=5
      op[j] = o;
    }
  };
  epilog(ac0, ag0, co0);
  epilog(ac1, ag1, co1);
}

extern "C" void kernel_launch(void* const* d_in, const int* in_sizes, int n_in,
                              void* d_out, int out_size, void* d_ws, size_t ws_size,
                              hipStream_t stream) {
  const float* events = (const float*)d_in[0];
  const float* w_in   = (const float*)d_in[1];
  const float* b_in   = (const float*)d_in[2];
  const float* w_gate = (const float*)d_in[3];
  const float* b_gate = (const float*)d_in[4];
  const float* tdec   = (const float*)d_in[5];
  float* out = (float*)d_out;

  float* ws   = (float*)d_ws;
  const size_t NP = (size_t)8 * COUT * PLANE;   // 2,097,152
  float* vmem = ws;
  float* sA   = ws + NP;
  float* sB   = ws + 2 * NP;

  // zero vmem + spikeA (spikeB fully written at t=0 before first read)
  hipMemsetAsync(d_ws, 0, 2 * NP * sizeof(float), stream);

  dim3 grid(256), block(1024);
  for (int t = 0; t < TT; ++t) {
    const float* ssrc = (t & 1) ? sB : sA;
    float*       sdst = (t & 1) ? sA : sB;
    hipLaunchKernelGGL(snn_step, grid, block, 0, stream,
                       events, w_in, b_in, w_gate, b_gate, tdec,
                       vmem, ssrc, sdst, out, t);
  }
}

// Round 5
// 895.897 us; speedup vs baseline: 1.1689x; 1.1498x over previous
//
#include <hip/hip_runtime.h>
#include <cmath>

// DTASNN embedding: T=5 recurrent steps, each = conv(x, w_in) + conv(spike_prev, w_gate)
// (both 64ch -> 128ch, 3x3 SAME), sigmoid-gated LIF update, hard reset, avg readout.
//
// R5 changes vs R4 (which was LDS-PIPE-bound: VALU:LDS = 1:1 in cycles, conflicts
// pushing LDS to ~77% busy while VALU sat at 38%):
//  - 4 output channels per thread (8 weight-sets, 32 accumulators): row pixels are
//    read from LDS into registers ONCE per ci (12 LDS reads) and reused by all 8
//    sets -> 576 FMAs per 12 LDS reads (2x R4's arithmetic intensity).
//  - block = (batch, co-quad, image-half): 8 x 16 x 2 = 256 blocks x 512 threads;
//    device-wide LDS traffic halves; VALU becomes the bottleneck pipe.
//  - half-boundary halo row fetched from global by 64 lanes (1 float4/ci, tiny).
//
// Per-output FMA chain order (ci -> w_in taps kh,kw -> w_gate taps kh,kw) is
// IDENTICAL to R2..R4 -> output bit-exact vs the passing kernels (absmax 0.0).
//
// ws layout (floats): vmem [2M] | spikeA [2M] | spikeB [2M]

#define HW    64
#define CIN   64
#define COUT  64
#define TT    5
#define PLANE (HW * HW)            // 4096
#define LSTRIDE 68                 // dwords per LDS row
#define HROWS   34                 // 1 top halo + 32 interior rows + 1 bottom halo
#define LPLANE  (HROWS * LSTRIDE + 4)  // +4: right-halo overhang of last row

// One input plane, 8 weight-sets (cur/gate x 4 co), 4-px strip.
// acc[0..3] = cur co0..co0+3, acc[4..7] = gate co0..co0+3.
__device__ __forceinline__ void conv_plane8(const float* __restrict__ lds,
    int h, int w0, const float* __restrict__ wci,  // = w + ci*9; row stride CIN*9
    int co0, float (*__restrict__ acc)[4])
{
  float v[3][6];                                   // img cols w0-1 .. w0+4, 3 rows
#pragma unroll
  for (int kh = 0; kh < 3; ++kh) {
    const float* row = lds + (h + kh) * LSTRIDE + w0;  // dword w0 = img col w0-4
    float4 q = *(const float4*)(row + 4);              // img cols w0..w0+3 (aligned)
    v[kh][0] = row[3];                                 // img col w0-1 } ds_read2_b32
    v[kh][5] = row[8];                                 // img col w0+4 }
    v[kh][1] = q.x; v[kh][2] = q.y; v[kh][3] = q.z; v[kh][4] = q.w;
  }
#pragma unroll
  for (int s = 0; s < 8; ++s) {
    const int co = co0 + (s & 3) + ((s >> 2) ? COUT : 0);
    const float* w = wci + (size_t)co * (CIN * 9);     // block-uniform -> s_loads
#pragma unroll
    for (int kh = 0; kh < 3; ++kh)
#pragma unroll
      for (int kw = 0; kw < 3; ++kw) {
        const float f = w[kh * 3 + kw];
#pragma unroll
        for (int j = 0; j < 4; ++j)
          acc[s][j] = fmaf(v[kh][j + kw], f, acc[s][j]);
      }
  }
}

__global__ __launch_bounds__(512) void snn_step(
    const float* __restrict__ events,
    const float* __restrict__ w_in,
    const float* __restrict__ b_in,
    const float* __restrict__ w_gate,
    const float* __restrict__ b_gate,
    const float* __restrict__ tdecay,
    float* __restrict__ vmem,
    const float* __restrict__ s_src,
    float* __restrict__ s_dst,
    float* __restrict__ outp,
    int t)
{
  __shared__ float lx[2 * LPLANE];   // event half-plane, double-buffered
  __shared__ float ls[2 * LPLANE];   // spike half-plane, double-buffered

  const int tid  = threadIdx.x;            // 0..511
  const int blk  = blockIdx.x;             // 256 = b(8) x co-quad(16) x half(2)
  const int b    = blk >> 5;
  const int rem  = blk & 31;
  const int co0  = (rem >> 1) * 4;
  const int half = rem & 1;

  const int hl = tid >> 4;                 // local row 0..31
  const int w0 = (tid & 15) * 4;           // 4-wide strip
  const int h  = half * 32 + hl;           // img row

  // Zero both buffers once. Interior (rows 1..32, dwords 4..67) rewritten each ci;
  // halo row 0/33 written only when it maps to a real img row; all else stays 0
  // (SAME padding; dword r*68+0 doubles as right halo col 64 of row r-1).
  for (int i = tid; i < 2 * LPLANE; i += 512) { lx[i] = 0.f; ls[i] = 0.f; }

  float acc[8][4];
#pragma unroll
  for (int s = 0; s < 8; ++s)
#pragma unroll
    for (int j = 0; j < 4; ++j) acc[s][j] = 0.f;

  // time-reversed events: step t reads events[b, TT-1-t]
  const float* evplane = events + (size_t)(b * TT + (TT - 1 - t)) * CIN * PLANE;
  const float* ssplane = s_src  + (size_t)b * CIN * PLANE;
  const float* evb = evplane + h * HW + w0;
  const float* ssb = ssplane + h * HW + w0;
  const int dbase = (hl + 1) * LSTRIDE + (w0 + 4);   // 16B-aligned interior slot

  // Halo duty for lanes 0..63: one float4 of the boundary row per plane per ci.
  const int  hp = (tid >> 5) & 1;          // 0 -> x plane, 1 -> s plane
  const int  hr = (tid >> 4) & 1;          // 0 -> LDS row 0 (img h0-1), 1 -> row 33 (img h0+32)
  const int  hc = tid & 15;
  const int  ir = hr ? (half * 32 + 32) : (half * 32 - 1);
  const bool hvalid = (tid < 64) && (ir >= 0) && (ir < HW);
  const float* hsrc = (hp ? ssplane : evplane) + (hvalid ? (ir * HW + hc * 4) : 0);
  const int  hdst = (hr ? 33 : 0) * LSTRIDE + hc * 4 + 4;

  // prefetch ci=0
  float4 x0 = *(const float4*)evb;
  float4 s0 = *(const float4*)ssb;
  float4 hv = hvalid ? *(const float4*)hsrc : make_float4(0.f, 0.f, 0.f, 0.f);

  __syncthreads();                         // zeroing complete before first stores

  for (int ci = 0; ci < CIN; ++ci) {
    const int pb = (ci & 1) * LPLANE;
    *(float4*)(lx + pb + dbase) = x0;
    *(float4*)(ls + pb + dbase) = s0;
    if (hvalid) *(float4*)((hp ? ls : lx) + pb + hdst) = hv;

    __syncthreads();                       // stores visible; prev buffer's readers done

    if (ci + 1 < CIN) {                    // prefetch after barrier: vmcnt(0) drain
      x0 = *(const float4*)(evb + (ci + 1) * PLANE);   // lands a compute-phase later
      s0 = *(const float4*)(ssb + (ci + 1) * PLANE);
      if (hvalid) hv = *(const float4*)(hsrc + (ci + 1) * PLANE);
    }

    conv_plane8(lx + pb, hl, w0, w_in   + ci * 9, co0, acc);
    conv_plane8(ls + pb, hl, w0, w_gate + ci * 9, co0, acc);
  }

  const float tf = (float)t;
  const bool t0 = (t == 0);
  const bool tL = (t == TT - 1);

#pragma unroll
  for (int c = 0; c < 4; ++c) {
    const int co = co0 + c;
    const float* ac = acc[c];
    const float* ag = acc[4 + c];
    const float bc = b_in[co]        + b_gate[co];
    const float bg = b_in[co + COUT] + b_gate[co + COUT];
    const float th = powf(tdecay[co], tf);        // THRESH=1.0
    const size_t base = (size_t)((b * COUT + co) * HW + h) * HW + w0;
    float* vp = vmem  + base;
    float* sp = s_dst + base;
    float* op = outp  + base;
#pragma unroll
    for (int j = 0; j < 4; ++j) {
      const float cur  = ac[j] + bc;
      const float gp   = ag[j] + bg;
      const float gate = 1.f / (1.f + expf(-gp));
      const float v    = gate * vp[j] + cur;      // vmem = gate*vmem + current
      const bool fired = (v >= th);               // heaviside(v - th)
      vp[j] = fired ? 0.f : v;                    // hard reset to VRESET=0
      sp[j] = fired ? 1.f : 0.f;
      float o = (t0 ? 0.f : op[j]) + (fired ? 1.f : 0.f);
      if (tL) o *= 0.2f;                          // mean over T=5
      op[j] = o;
    }
  }
}

extern "C" void kernel_launch(void* const* d_in, const int* in_sizes, int n_in,
                              void* d_out, int out_size, void* d_ws, size_t ws_size,
                              hipStream_t stream) {
  const float* events = (const float*)d_in[0];
  const float* w_in   = (const float*)d_in[1];
  const float* b_in   = (const float*)d_in[2];
  const float* w_gate = (const float*)d_in[3];
  const float* b_gate = (const float*)d_in[4];
  const float* tdec   = (const float*)d_in[5];
  float* out = (float*)d_out;

  float* ws   = (float*)d_ws;
  const size_t NP = (size_t)8 * COUT * PLANE;   // 2,097,152
  float* vmem = ws;
  float* sA   = ws + NP;
  float* sB   = ws + 2 * NP;

  // zero vmem + spikeA (spikeB fully written at t=0 before first read)
  hipMemsetAsync(d_ws, 0, 2 * NP * sizeof(float), stream);

  dim3 grid(256), block(512);
  for (int t = 0; t < TT; ++t) {
    const float* ssrc = (t & 1) ? sB : sA;
    float*       sdst = (t & 1) ? sA : sB;
    hipLaunchKernelGGL(snn_step, grid, block, 0, stream,
                       events, w_in, b_in, w_gate, b_gate, tdec,
                       vmem, ssrc, sdst, out, t);
  }
}

// Round 6
// 314.069 us; speedup vs baseline: 3.3343x; 2.8525x over previous
//
#include <hip/hip_runtime.h>
#include <cmath>

// DTASNN embedding via bf16 triple-limb MFMA implicit conv.
//
// Both conv inputs are BINARY {0,1} -> exact in bf16. Weights split w = hi+mid+lo
// (3 bf16 limbs, residual <= 2^-33|w|): MFMA computes the exact sum with only
// fp32 accumulation-order noise (~3e-6) -- same class as the passing fp32 kernel
// vs the np reference (which matched with 0 flips). Stack events(64)+spikes(64)
// as K=128; cur+gate = M=128 outputs; N = pixels.
//
// Per step: 256 blocks = (b, row-pair). LDS stages 4 rows x 66 cols x 128 ch bf16,
// channel-minor with +8 pad (272B px stride, odd-17 quads -> conflict-free b128).
// Wave g owns 16 output rows o' = g*16.. (i<8: cur co=g*8+i, i>=8: gate same co ->
// LIF pairing is one shfl_xor(32)). 8 px-tiles/wave, mfma_f32_16x16x32_bf16,
// each B-frag b128 feeds 3 limb-MFMAs. A-frags from prepped global layout (L2).
// Spikes stored [b][h][w][c] bf16 -> next step's S staging is a raw coalesced copy.
//
// ws: vmem fp32 8MB | sA bf16 4MB | sB bf16 4MB | Wprep 864KB

typedef __attribute__((ext_vector_type(8))) short short8;
typedef __attribute__((ext_vector_type(4))) float floatx4;

#define HW 64
#define TT 5
#define PLANE 4096
#define WP_ELEMS 147456            // per limb: 9 taps * 4 ks * 4 q * 128 o * 8 j
#define CDIM 136                   // 128 ch + 8 pad (ushort)
#define UELEMS (4 * 66 * CDIM)     // 35904 ushorts = 71808 B LDS

__device__ __forceinline__ ushort f2bf_rne(float f) {
  uint u = __float_as_uint(f);
  return (ushort)((u + 0x7FFFu + ((u >> 16) & 1u)) >> 16);
}
__device__ __forceinline__ float bf2f(ushort h) {
  return __uint_as_float(((uint)h) << 16);
}

// Wprep[limb][tap][ks][q][o'][j]: A-frag for lane(m=lane&15,q=lane>>4) of o-group g
// is 8 contiguous ushorts at ((tap*16+ks*4+q)*128 + g*16+m)*8 (+limb*WP_ELEMS).
// o' = g*16+i: i<8 -> cur co=g*8+i (weight row co), i>=8 -> gate (weight row 64+co).
// c<64 -> w_in (events path), c>=64 -> w_gate (spike path).
__global__ __launch_bounds__(256) void prep_weights(
    const float* __restrict__ w_in, const float* __restrict__ w_gate,
    ushort* __restrict__ Wp)
{
  int idx = blockIdx.x * 256 + threadIdx.x;
  if (idx >= WP_ELEMS) return;
  int j   = idx & 7;
  int o   = (idx >> 3) & 127;
  int q   = (idx >> 10) & 3;
  int ks  = (idx >> 12) & 3;
  int tap = idx >> 14;                       // 0..8 (kh*3+kw)
  int c   = ks * 32 + q * 8 + j;             // 0..127
  int g = o >> 4, i = o & 15;
  int row = (i >> 3) * 64 + (g * 8 + (i & 7));
  float w = (c < 64) ? w_in[(row * 64 + c) * 9 + tap]
                     : w_gate[(row * 64 + (c - 64)) * 9 + tap];
  ushort h = f2bf_rne(w);
  float r1 = w - bf2f(h);
  ushort m = f2bf_rne(r1);
  float r2 = r1 - bf2f(m);
  ushort l = f2bf_rne(r2);
  Wp[idx] = h;
  Wp[WP_ELEMS + idx] = m;
  Wp[2 * WP_ELEMS + idx] = l;
}

__global__ __launch_bounds__(512, 2) void snn_step(
    const float*  __restrict__ events,
    const ushort* __restrict__ Wp,
    const float*  __restrict__ b_in,
    const float*  __restrict__ b_gate,
    const float*  __restrict__ tdec,
    float*        __restrict__ vmem,     // [b][co][h][w] fp32
    const ushort* __restrict__ s_src,    // [b][h][w][c] bf16
    ushort*       __restrict__ s_dst,
    float*        __restrict__ outp,     // [b][co][h][w] fp32
    int t)
{
  __shared__ ushort U[UELEMS];   // [row4][col66][c136]: rows r0-1..r0+2, col=img+1

  const int tid = threadIdx.x;
  const int b   = blockIdx.x >> 5;
  const int br  = blockIdx.x & 31;           // row-pair: img rows 2br, 2br+1
  const int r0  = 2 * br;

  const int lane = tid & 63;
  const int g    = tid >> 6;                 // wave = o-group 0..7
  const int ln   = lane & 15;                // = A's m = B's n (px col in tile)
  const int q    = lane >> 4;                // k-octet group 0..3

  // ---- zero LDS (halo rows/cols stay 0 = SAME padding) ----
  for (int i = tid; i < UELEMS / 8; i += 512) ((short8*)U)[i] = short8{0,0,0,0,0,0,0,0};
  __syncthreads();

  // ---- stage events (fp32 {0,1} -> bf16, transpose to ch-minor), c slots 0..63 ----
  {
    const int c    = tid >> 3;               // 0..63
    const int row  = (tid >> 1) & 3;         // lds row
    const int half = tid & 1;                // col half
    const int r    = r0 + row - 1;
    if (r >= 0 && r < HW) {
      const float* src = events + ((size_t)(b * TT + (TT - 1 - t)) * 64 + c) * PLANE
                         + r * HW + half * 32;
      float v[32];
#pragma unroll
      for (int k = 0; k < 8; ++k) {
        float4 f = ((const float4*)src)[k];
        v[4*k+0] = f.x; v[4*k+1] = f.y; v[4*k+2] = f.z; v[4*k+3] = f.w;
      }
#pragma unroll
      for (int k = 0; k < 32; ++k)
        U[(row * 66 + 1 + half * 32 + k) * CDIM + c] = (v[k] != 0.f) ? 0x3F80 : 0;
    }
  }
  // ---- stage spikes (raw bf16 copy, already ch-minor), c slots 64..127 ----
  {
    const int row  = tid >> 7;               // 0..3
    const int col  = (tid >> 1) & 63;        // img col
    const int half = tid & 1;
    const int r    = r0 + row - 1;
    if (r >= 0 && r < HW) {
      const ushort* src = s_src + ((size_t)((b * HW + r) * HW + col)) * 64 + half * 32;
      ushort* dst = U + (row * 66 + col + 1) * CDIM + 64 + half * 32;
#pragma unroll
      for (int k = 0; k < 4; ++k)
        *(short8*)(dst + 8 * k) = *(const short8*)(src + 8 * k);
    }
  }
  __syncthreads();

  // ---- MFMA main loop: acc[tt] = 16 o' x 16 px tile tt ----
  floatx4 acc[8];
#pragma unroll
  for (int tt = 0; tt < 8; ++tt) acc[tt] = floatx4{0.f, 0.f, 0.f, 0.f};

  const int laneB = ln * CDIM + q * 8;                  // B-frag lane offset (ushorts)
  const ushort* wpl = Wp + (size_t)q * 1024 + (g * 16 + ln) * 8;  // A-frag lane base

  for (int tap = 0; tap < 9; ++tap) {
    const int kh = tap / 3, kw = tap % 3;
    short8 Ah[4], Am[4], Al[4];
    const ushort* wpt = wpl + tap * 16384;
#pragma unroll
    for (int ks = 0; ks < 4; ++ks) {
      Ah[ks] = *(const short8*)(wpt + ks * 4096);
      Am[ks] = *(const short8*)(wpt + WP_ELEMS + ks * 4096);
      Al[ks] = *(const short8*)(wpt + 2 * WP_ELEMS + ks * 4096);
    }
#pragma unroll
    for (int tt = 0; tt < 8; ++tt) {
      const int xbase = ((tt >> 2) + kh) * 66 * CDIM + ((tt & 3) * 16 + kw) * CDIM;
#pragma unroll
      for (int ks = 0; ks < 4; ++ks) {
        short8 B = *(const short8*)(U + xbase + ks * 32 + laneB);
        acc[tt] = __builtin_amdgcn_mfma_f32_16x16x32_bf16(Ah[ks], B, acc[tt], 0, 0, 0);
        acc[tt] = __builtin_amdgcn_mfma_f32_16x16x32_bf16(Am[ks], B, acc[tt], 0, 0, 0);
        acc[tt] = __builtin_amdgcn_mfma_f32_16x16x32_bf16(Al[ks], B, acc[tt], 0, 0, 0);
      }
    }
  }

  // ---- LIF epilogue. D layout: col(px) = lane&15, row(o' in 16) = q*4+reg.
  // Lane pairing: lane l (q<2, cur rows i=q*4+r) <-> l^32 (gate rows i+8, same co,px).
  const bool t0 = (t == 0), tL = (t == TT - 1);
  float bc[4], bg[4], th[4];
  {
    const int qe = q & 1;
#pragma unroll
    for (int r = 0; r < 4; ++r) {
      const int co = g * 8 + qe * 4 + r;
      bc[r] = b_in[co] + b_gate[co];
      bg[r] = b_in[64 + co] + b_gate[64 + co];
      th[r] = powf(tdec[co], (float)t);       // THRESH=1.0
    }
  }
#pragma unroll
  for (int tt = 0; tt < 8; ++tt) {
    const int hh  = r0 + (tt >> 2);
    const int col = (tt & 3) * 16 + ln;
#pragma unroll
    for (int r = 0; r < 4; ++r) {
      const float other = __shfl_xor(acc[tt][r], 32, 64);
      if (q < 2) {
        const int co = g * 8 + q * 4 + r;
        const size_t idx  = ((size_t)((b * 64 + co) * HW + hh)) * HW + col;
        const size_t sidx = ((size_t)((b * HW + hh) * HW + col)) * 64 + co;
        const float cur  = acc[tt][r] + bc[r];
        const float gp   = other + bg[r];
        const float gate = 1.f / (1.f + expf(-gp));
        const float v    = gate * vmem[idx] + cur;    // vmem = gate*vmem + current
        const bool fired = (v >= th[r]);              // heaviside(v - thresh_t)
        vmem[idx]  = fired ? 0.f : v;                 // hard reset to VRESET=0
        s_dst[sidx] = fired ? (ushort)0x3F80 : (ushort)0;
        float o = (t0 ? 0.f : outp[idx]) + (fired ? 1.f : 0.f);
        if (tL) o *= 0.2f;                            // mean over T=5
        outp[idx] = o;
      }
    }
  }
}

extern "C" void kernel_launch(void* const* d_in, const int* in_sizes, int n_in,
                              void* d_out, int out_size, void* d_ws, size_t ws_size,
                              hipStream_t stream) {
  const float* events = (const float*)d_in[0];
  const float* w_in   = (const float*)d_in[1];
  const float* b_in   = (const float*)d_in[2];
  const float* w_gate = (const float*)d_in[3];
  const float* b_gate = (const float*)d_in[4];
  const float* tdec   = (const float*)d_in[5];
  float* out = (float*)d_out;

  char* base = (char*)d_ws;
  float*  vmem = (float*)base;                       //  8 MB fp32 [b][co][h][w]
  ushort* sA   = (ushort*)(base + 8388608);          //  4 MB bf16 [b][h][w][c]
  ushort* sB   = (ushort*)(base + 12582912);         //  4 MB
  ushort* Wp   = (ushort*)(base + 16777216);         //  864 KB

  hipMemsetAsync(base, 0, 12582912, stream);         // vmem + sA = 0

  hipLaunchKernelGGL(prep_weights, dim3(576), dim3(256), 0, stream, w_in, w_gate, Wp);

  for (int t = 0; t < TT; ++t) {
    const ushort* ssrc = (t & 1) ? sB : sA;
    ushort*       sdst = (t & 1) ? sA : sB;
    hipLaunchKernelGGL(snn_step, dim3(256), dim3(512), 0, stream,
                       events, Wp, b_in, b_gate, tdec, vmem, ssrc, sdst, out, t);
  }
}

// Round 7
// 286.047 us; speedup vs baseline: 3.6609x; 1.0980x over previous
//
#include <hip/hip_runtime.h>
#include <cmath>

// DTASNN embedding via bf16 triple-limb MFMA implicit conv.
//
// Both conv inputs are BINARY {0,1} -> exact in bf16. Weights split w = hi+mid+lo
// (3 bf16 limbs, residual <= 2^-33|w|): MFMA computes the exact sum with only
// fp32 accumulation-order noise -- verified absmax 0.0 in R6. Stack events(64)+
// spikes(64) as K=128; cur+gate = M=128 outputs; N = pixels.
//
// R7 vs R6 (which was latency-bound: all pipes ~20%, 2 waves/SIMD, A-frag L2
// latency exposed at tap boundaries):
//  - 1024 threads = 16 waves = 4 waves/SIMD. Wave (g, half) computes o-group g
//    on 4 px-tiles (img row r0+half). Per-acc MFMA sequence identical to R6
//    -> bit-exact output. Total LDS traffic unchanged; A traffic 2x (L2-hit).
//  - staging work spread over 1024 threads (each thread half of R6's share).
//
// ws: vmem fp32 8MB | sA bf16 4MB | sB bf16 4MB | Wprep 864KB

typedef __attribute__((ext_vector_type(8))) short short8;
typedef __attribute__((ext_vector_type(4))) float floatx4;

#define HW 64
#define TT 5
#define PLANE 4096
#define WP_ELEMS 147456            // per limb: 9 taps * 4 ks * 4 q * 128 o * 8 j
#define CDIM 136                   // 128 ch + 8 pad (ushort): odd-17 quads, no conflicts
#define UELEMS (4 * 66 * CDIM)     // 35904 ushorts = 71808 B LDS

__device__ __forceinline__ ushort f2bf_rne(float f) {
  uint u = __float_as_uint(f);
  return (ushort)((u + 0x7FFFu + ((u >> 16) & 1u)) >> 16);
}
__device__ __forceinline__ float bf2f(ushort h) {
  return __uint_as_float(((uint)h) << 16);
}

// Wprep[limb][tap][ks][q][o'][j]: A-frag for lane(m=lane&15,q=lane>>4) of o-group g
// is 8 contiguous ushorts at ((tap*16+ks*4+q)*128 + g*16+m)*8 (+limb*WP_ELEMS).
// o' = g*16+i: i<8 -> cur co=g*8+i, i>=8 -> gate (weight row 64+co).
// c<64 -> w_in (events path), c>=64 -> w_gate (spike path).
__global__ __launch_bounds__(256) void prep_weights(
    const float* __restrict__ w_in, const float* __restrict__ w_gate,
    ushort* __restrict__ Wp)
{
  int idx = blockIdx.x * 256 + threadIdx.x;
  if (idx >= WP_ELEMS) return;
  int j   = idx & 7;
  int o   = (idx >> 3) & 127;
  int q   = (idx >> 10) & 3;
  int ks  = (idx >> 12) & 3;
  int tap = idx >> 14;                       // 0..8 (kh*3+kw)
  int c   = ks * 32 + q * 8 + j;             // 0..127
  int g = o >> 4, i = o & 15;
  int row = (i >> 3) * 64 + (g * 8 + (i & 7));
  float w = (c < 64) ? w_in[(row * 64 + c) * 9 + tap]
                     : w_gate[(row * 64 + (c - 64)) * 9 + tap];
  ushort h = f2bf_rne(w);
  float r1 = w - bf2f(h);
  ushort m = f2bf_rne(r1);
  float r2 = r1 - bf2f(m);
  ushort l = f2bf_rne(r2);
  Wp[idx] = h;
  Wp[WP_ELEMS + idx] = m;
  Wp[2 * WP_ELEMS + idx] = l;
}

__global__ __launch_bounds__(1024, 4) void snn_step(
    const float*  __restrict__ events,
    const ushort* __restrict__ Wp,
    const float*  __restrict__ b_in,
    const float*  __restrict__ b_gate,
    const float*  __restrict__ tdec,
    float*        __restrict__ vmem,     // [b][co][h][w] fp32
    const ushort* __restrict__ s_src,    // [b][h][w][c] bf16
    ushort*       __restrict__ s_dst,
    float*        __restrict__ outp,     // [b][co][h][w] fp32
    int t)
{
  __shared__ ushort U[UELEMS];   // [row4][col66][c136]: rows r0-1..r0+2, col=img+1

  const int tid = threadIdx.x;               // 0..1023
  const int b   = blockIdx.x >> 5;
  const int br  = blockIdx.x & 31;           // row-pair: img rows 2br, 2br+1
  const int r0  = 2 * br;

  const int lane = tid & 63;
  const int g    = (tid >> 6) & 7;           // o-group 0..7
  const int half = tid >> 9;                 // tile-half 0/1 (img row r0+half)
  const int ln   = lane & 15;                // = A's m = B's n (px col in tile)
  const int q    = lane >> 4;                // k-octet group 0..3

  // ---- zero LDS (halo rows/cols stay 0 = SAME padding) ----
  for (int i = tid; i < UELEMS / 8; i += 1024) ((short8*)U)[i] = short8{0,0,0,0,0,0,0,0};
  __syncthreads();

  // ---- stage events (fp32 {0,1} -> bf16, transpose to ch-minor), c slots 0..63 ----
  {
    const int c   = tid & 63;                // channel
    const int row = (tid >> 6) & 3;          // lds row 0..3
    const int seg = (tid >> 8) & 3;          // 16-px segment
    const int r   = r0 + row - 1;
    if (r >= 0 && r < HW) {
      const float* src = events + ((size_t)(b * TT + (TT - 1 - t)) * 64 + c) * PLANE
                         + r * HW + seg * 16;
      float v[16];
#pragma unroll
      for (int k = 0; k < 4; ++k) {
        float4 f = ((const float4*)src)[k];
        v[4*k+0] = f.x; v[4*k+1] = f.y; v[4*k+2] = f.z; v[4*k+3] = f.w;
      }
#pragma unroll
      for (int k = 0; k < 16; ++k)
        U[(row * 66 + 1 + seg * 16 + k) * CDIM + c] = (v[k] != 0.f) ? 0x3F80 : 0;
    }
  }
  // ---- stage spikes (raw bf16 copy, already ch-minor), c slots 64..127 ----
  {
    const int col   = tid & 63;              // img col
    const int row   = (tid >> 6) & 3;        // lds row 0..3
    const int chunk = (tid >> 8) & 3;        // 16-ch chunk
    const int r     = r0 + row - 1;
    if (r >= 0 && r < HW) {
      const ushort* src = s_src + ((size_t)((b * HW + r) * HW + col)) * 64 + chunk * 16;
      ushort* dst = U + (row * 66 + col + 1) * CDIM + 64 + chunk * 16;
      *(short8*)(dst)     = *(const short8*)(src);
      *(short8*)(dst + 8) = *(const short8*)(src + 8);
    }
  }
  __syncthreads();

  // ---- MFMA main loop: acc[tt] = 16 o' x 16 px, tile (half*4 + tt) ----
  floatx4 acc[4];
#pragma unroll
  for (int tt = 0; tt < 4; ++tt) acc[tt] = floatx4{0.f, 0.f, 0.f, 0.f};

  const int laneB = ln * CDIM + q * 8;                  // B-frag lane offset (ushorts)
  const ushort* wpl = Wp + (size_t)q * 1024 + (g * 16 + ln) * 8;  // A-frag lane base

  for (int tap = 0; tap < 9; ++tap) {
    const int kh = tap / 3, kw = tap % 3;
    short8 Ah[4], Am[4], Al[4];
    const ushort* wpt = wpl + tap * 16384;
#pragma unroll
    for (int ks = 0; ks < 4; ++ks) {
      Ah[ks] = *(const short8*)(wpt + ks * 4096);
      Am[ks] = *(const short8*)(wpt + WP_ELEMS + ks * 4096);
      Al[ks] = *(const short8*)(wpt + 2 * WP_ELEMS + ks * 4096);
    }
#pragma unroll
    for (int tt = 0; tt < 4; ++tt) {
      const int xbase = (half + kh) * 66 * CDIM + (tt * 16 + kw) * CDIM;
#pragma unroll
      for (int ks = 0; ks < 4; ++ks) {
        short8 B = *(const short8*)(U + xbase + ks * 32 + laneB);
        acc[tt] = __builtin_amdgcn_mfma_f32_16x16x32_bf16(Ah[ks], B, acc[tt], 0, 0, 0);
        acc[tt] = __builtin_amdgcn_mfma_f32_16x16x32_bf16(Am[ks], B, acc[tt], 0, 0, 0);
        acc[tt] = __builtin_amdgcn_mfma_f32_16x16x32_bf16(Al[ks], B, acc[tt], 0, 0, 0);
      }
    }
  }

  // ---- LIF epilogue. D layout: col(px) = lane&15, row(o' in 16) = q*4+reg.
  // Lane pairing: lane l (q<2, cur rows i=q*4+r) <-> l^32 (gate rows i+8, same co,px).
  const bool t0 = (t == 0), tL = (t == TT - 1);
  float bc[4], bg[4], th[4];
  {
    const int qe = q & 1;
#pragma unroll
    for (int r = 0; r < 4; ++r) {
      const int co = g * 8 + qe * 4 + r;
      bc[r] = b_in[co] + b_gate[co];
      bg[r] = b_in[64 + co] + b_gate[64 + co];
      th[r] = powf(tdec[co], (float)t);       // THRESH=1.0
    }
  }
  const int hh = r0 + half;
#pragma unroll
  for (int tt = 0; tt < 4; ++tt) {
    const int col = tt * 16 + ln;
#pragma unroll
    for (int r = 0; r < 4; ++r) {
      const float other = __shfl_xor(acc[tt][r], 32, 64);
      if (q < 2) {
        const int co = g * 8 + q * 4 + r;
        const size_t idx  = ((size_t)((b * 64 + co) * HW + hh)) * HW + col;
        const size_t sidx = ((size_t)((b * HW + hh) * HW + col)) * 64 + co;
        const float cur  = acc[tt][r] + bc[r];
        const float gp   = other + bg[r];
        const float gate = 1.f / (1.f + expf(-gp));
        const float v    = gate * vmem[idx] + cur;    // vmem = gate*vmem + current
        const bool fired = (v >= th[r]);              // heaviside(v - thresh_t)
        vmem[idx]  = fired ? 0.f : v;                 // hard reset to VRESET=0
        s_dst[sidx] = fired ? (ushort)0x3F80 : (ushort)0;
        float o = (t0 ? 0.f : outp[idx]) + (fired ? 1.f : 0.f);
        if (tL) o *= 0.2f;                            // mean over T=5
        outp[idx] = o;
      }
    }
  }
}

extern "C" void kernel_launch(void* const* d_in, const int* in_sizes, int n_in,
                              void* d_out, int out_size, void* d_ws, size_t ws_size,
                              hipStream_t stream) {
  const float* events = (const float*)d_in[0];
  const float* w_in   = (const float*)d_in[1];
  const float* b_in   = (const float*)d_in[2];
  const float* w_gate = (const float*)d_in[3];
  const float* b_gate = (const float*)d_in[4];
  const float* tdec   = (const float*)d_in[5];
  float* out = (float*)d_out;

  char* base = (char*)d_ws;
  float*  vmem = (float*)base;                       //  8 MB fp32 [b][co][h][w]
  ushort* sA   = (ushort*)(base + 8388608);          //  4 MB bf16 [b][h][w][c]
  ushort* sB   = (ushort*)(base + 12582912);         //  4 MB
  ushort* Wp   = (ushort*)(base + 16777216);         //  864 KB

  hipMemsetAsync(base, 0, 12582912, stream);         // vmem + sA = 0

  hipLaunchKernelGGL(prep_weights, dim3(576), dim3(256), 0, stream, w_in, w_gate, Wp);

  for (int t = 0; t < TT; ++t) {
    const ushort* ssrc = (t & 1) ? sB : sA;
    ushort*       sdst = (t & 1) ? sA : sB;
    hipLaunchKernelGGL(snn_step, dim3(256), dim3(1024), 0, stream,
                       events, Wp, b_in, b_gate, tdec, vmem, ssrc, sdst, out, t);
  }
}